// Round 1
// baseline (1335.230 us; speedup 1.0000x reference)
//
#include <hip/hip_runtime.h>
#include <stdint.h>

// ---------------------------------------------------------------------------
// Fused 4-layer mini-BERT (B=32768, SEQ=4, D=128, H=4, DH=64) for gfx950.
// One WG = 32 batches (128 rows). 4 waves; each wave owns 2 groups of 16 rows
// (4 batches). All intermediates live in LDS/registers; weights staged into a
// double-buffered LDS slot from a bf16-transposed copy prepared in d_ws.
// ---------------------------------------------------------------------------

typedef __attribute__((ext_vector_type(8))) short    bf16x8;  // 8 bf16 (4 VGPRs)
typedef __attribute__((ext_vector_type(4))) _Float16 f16x4;   // 4 fp16 (2 VGPRs)
typedef __attribute__((ext_vector_type(4))) float    f32x4;

#define MFMA_BF(a,b,c) __builtin_amdgcn_mfma_f32_16x16x32_bf16((a),(b),(c),0,0,0)
#define MFMA_H(a,b,c)  __builtin_amdgcn_mfma_f32_16x16x16f16((a),(b),(c),0,0,0)

__device__ __forceinline__ unsigned short f2bf(float f){
  unsigned u = __float_as_uint(f);
  u += 0x7FFFu + ((u>>16)&1u);          // RNE
  return (unsigned short)(u>>16);
}
__device__ __forceinline__ float bf2f(unsigned short h){
  return __uint_as_float(((unsigned)h)<<16);
}

// ---------------- weight prep layout in d_ws (bf16 elements) ----------------
// wqT/wkT/wvT: 16 blocks (l*4+h) of [f=64][d pitch 136]   (B-frag: W[d][f] -> [f][d])
// woT:         16 blocks (l*4+h) of [n=128][k pitch 72]   (wo[h*64+k][n] -> [n][k])
// w1T:          4 blocks (l)      of [n=64][k pitch 136]
// w2T:          4 blocks (l)      of [n=128][k pitch 72]
#define WQT 0
#define WKT 139264
#define WVT 278528
#define WOT 417792
#define W1TO 565248
#define W2TO 600064
#define WTOT 636928

__global__ void prep_kernel(const float* __restrict__ wq, const float* __restrict__ wk,
                            const float* __restrict__ wv, const float* __restrict__ wo,
                            const float* __restrict__ w1, const float* __restrict__ w2,
                            unsigned short* __restrict__ ws){
  int e = blockIdx.x*256 + threadIdx.x;
  if (e >= WTOT) return;
  float v = 0.f;
  if (e < WOT){                          // wq/wk/wv transposed per (l,h)
    const float* src = (e<WKT)? wq : (e<WVT)? wk : wv;
    int r = (e<WKT)? e : (e<WVT)? (e-WKT) : (e-WVT);
    int blk = r/8704, rem = r%8704;      // blk = l*4+h
    int f = rem/136, d = rem%136;
    if (d<128) v = src[((size_t)blk*128 + d)*64 + f];
  } else if (e < W1TO){                  // woT per (l,h)
    int r = e-WOT; int blk = r/9216, rem = r%9216;
    int n = rem/72, kk = rem%72;
    int l = blk>>2, h = blk&3;
    if (kk<64) v = wo[((size_t)l*256 + h*64 + kk)*128 + n];
  } else if (e < W2TO){                  // w1T per l
    int r = e-W1TO; int l = r/8704, rem = r%8704;
    int n = rem/136, kk = rem%136;
    if (kk<128) v = w1[((size_t)l*128 + kk)*64 + n];
  } else {                               // w2T per l
    int r = e-W2TO; int l = r/9216, rem = r%9216;
    int n = rem/72, kk = rem%72;
    if (kk<64) v = w2[((size_t)l*64 + kk)*128 + n];
  }
  ws[e] = f2bf(v);
}

// ---------------- LDS layout ----------------
// per-group (16 rows) region, stride PG:
//   XOFF : x residual      bf16 [16][136]   (4352 B)
//   QOFF : Q_h / ctx_h / X2-low   bf16 [16][72] (X2 = bf16[16][136] overlays QOFF..)
//   KOFF : K_h / X2-high   bf16 [16][72]
//   VOFF : V^T_h fp16 [64][20]  /  h1 bf16 [16][72]
// then 2 weight slots of 18432 B.
#define PG    11520
#define XOFF  0
#define QOFF  4352
#define KOFF  6656
#define VOFF  8960
#define WSOFF 92160
#define SLOTSZ 18432
#define LDSSZ 129024

__device__ __forceinline__ void stage_src(int s, const unsigned short* ws,
                                          const unsigned short*& p, int& n16){
  int l = s/18, r = s%18;
  if (r < 16){
    int h = r>>2, t = r&3;
    if      (t==0){ p = ws + WQT + (l*4+h)*8704; n16 = 1088; }
    else if (t==1){ p = ws + WKT + (l*4+h)*8704; n16 = 1088; }
    else if (t==2){ p = ws + WVT + (l*4+h)*8704; n16 = 1088; }
    else          { p = ws + WOT + (l*4+h)*9216; n16 = 1152; }
  } else if (r==16){ p = ws + W1TO + l*8704; n16 = 1088; }
  else             { p = ws + W2TO + l*9216; n16 = 1152; }
}

__global__ __launch_bounds__(256,1) void bert_kernel(
    const float* __restrict__ emb,
    const float* __restrict__ bq, const float* __restrict__ bk, const float* __restrict__ bv,
    const float* __restrict__ bo,
    const float* __restrict__ ln1g, const float* __restrict__ ln1b,
    const float* __restrict__ fb1, const float* __restrict__ fb2,
    const float* __restrict__ ln2g, const float* __restrict__ ln2b,
    const unsigned short* __restrict__ ws,
    float* __restrict__ out)
{
  __shared__ __align__(16) char smem[LDSSZ];
  const int tid  = threadIdx.x;
  const int wid  = tid>>6;        // wave 0..3
  const int lane = tid&63;
  const int lnid = lane&15;       // MFMA n/m lane id
  const int qid  = lane>>4;       // MFMA quad
  const int batch0 = blockIdx.x*32;
  const f32x4 ZV = {0.f,0.f,0.f,0.f};

  // ---- initial X load: embeddings[:, :4, :] -> bf16 LDS, per-wave groups ----
  #pragma unroll
  for (int gg=0; gg<2; ++gg){
    int g = wid*2+gg;
    char* Xb = smem + g*PG + XOFF;
    int row = lane>>2;                       // 0..15
    int col = (lane&3)*32;                   // 0/32/64/96
    const float* src = emb + ((size_t)(batch0 + g*4 + (row>>2))*6 + (row&3))*128 + col;
    #pragma unroll
    for (int i=0;i<8;++i){
      float4 v = *(const float4*)(src + i*4);
      unsigned w0 = f2bf(v.x) | ((unsigned)f2bf(v.y)<<16);
      unsigned w1_ = f2bf(v.z) | ((unsigned)f2bf(v.w)<<16);
      *(uint2*)(Xb + row*272 + (col+i*4)*2) = make_uint2(w0,w1_);
    }
  }

  // ---- passthrough outputs: positive_pair (row 4), negative_pairs (row 5) ----
  {
    const float* ebase = emb + (size_t)batch0*768;
    float* o1 = out + 4194304 + (size_t)batch0*128;
    float* o2 = out + 8388608 + (size_t)batch0*128;
    #pragma unroll
    for (int i=0;i<8;++i){
      int f4 = i*256 + tid;                  // 0..2047 float4s
      int bl = f4>>6, rem = f4&63;
      if (rem<32)
        *(float4*)(o1 + bl*128 + rem*4) = *(const float4*)(ebase + bl*768 + 512 + rem*4);
      else
        *(float4*)(o2 + bl*128 + (rem-32)*4) = *(const float4*)(ebase + bl*768 + 640 + (rem-32)*4);
    }
  }

  // ---- prologue: stage 0 (layer0 WqT h0) into slot 0 ----
  {
    const unsigned short* sp; int n16; stage_src(0, ws, sp, n16);
    #pragma unroll
    for (int i=0;i<5;++i){ int idx=i*256+tid; if (idx<n16)
        *(uint4*)(smem+WSOFF+idx*16) = ((const uint4*)sp)[idx]; }
  }
  __syncthreads();

  f32x4  pacc[2][8];        // proj accumulators per group, 8 n-tiles
  bf16x8 xfrag[2][4];       // X A-fragments per group, K=128 in 4 chunks
  int sidx = 0;

  for (int l=0; l<4; ++l){
    #pragma unroll
    for (int g=0; g<2; ++g){
      char* Xb = smem + (wid*2+g)*PG + XOFF;
      #pragma unroll
      for (int kc=0;kc<4;++kc)
        xfrag[g][kc] = *(const bf16x8*)(Xb + lnid*272 + kc*64 + qid*16);
    }
    #pragma unroll
    for (int g=0;g<2;++g){
      #pragma unroll
      for (int nt=0;nt<8;++nt) pacc[g][nt] = ZV;
    }

    for (int ph=0; ph<18; ++ph){
      char* slot = smem + WSOFF + (sidx&1)*SLOTSZ;

      // prefetch next weight stage into registers
      uint4 pfbuf[5]; int nn16 = 0;
      if (sidx+1 < 72){
        const unsigned short* sp; stage_src(sidx+1, ws, sp, nn16);
        #pragma unroll
        for (int i=0;i<5;++i){ int idx=i*256+tid; if (idx<nn16) pfbuf[i] = ((const uint4*)sp)[idx]; }
      }

      if (ph < 16){
        int h = ph>>2, t = ph&3;
        if (t < 3){
          // ---------------- Q/K/V gemm for head h ----------------
          const float* bias_base = (t==0? bq : (t==1? bk : bv)) + (l*4+h)*64;
          #pragma unroll
          for (int nt=0; nt<4; ++nt){
            f32x4 a0 = ZV, a1 = ZV;
            #pragma unroll
            for (int kc=0; kc<4; ++kc){
              bf16x8 bw = *(const bf16x8*)(slot + ((nt*16+lnid)*136 + kc*32)*2 + qid*16);
              a0 = MFMA_BF(xfrag[0][kc], bw, a0);
              a1 = MFMA_BF(xfrag[1][kc], bw, a1);
            }
            float bias = bias_base[nt*16+lnid];
            if (t < 2){
              int off = (t==0)? QOFF : KOFF;
              #pragma unroll
              for (int g=0;g<2;++g){
                char* base = smem + (wid*2+g)*PG + off;
                f32x4 a = g? a1 : a0;
                #pragma unroll
                for (int r=0;r<4;++r)
                  *(unsigned short*)(base + (qid*4+r)*144 + (nt*16+lnid)*2) = f2bf(a[r]+bias);
              }
            } else {
              // V stored transposed [f][t] as fp16 (C-layout regs are t-contiguous)
              #pragma unroll
              for (int g=0;g<2;++g){
                char* base = smem + (wid*2+g)*PG + VOFF;
                f32x4 a = g? a1 : a0;
                f16x4 hv;
                #pragma unroll
                for (int r=0;r<4;++r) hv[r] = (_Float16)(a[r]+bias);
                *(f16x4*)(base + ((nt*16+lnid)*20 + qid*4)*2) = hv;
              }
            }
          }
        } else {
          // ---------------- attention (head h) + proj partial ----------------
          #pragma unroll
          for (int g=0;g<2;++g){
            char* gb = smem + (wid*2+g)*PG;
            bf16x8 qf0 = *(const bf16x8*)(gb+QOFF + lnid*144 + qid*16);
            bf16x8 qf1 = *(const bf16x8*)(gb+QOFF + lnid*144 + 64 + qid*16);
            bf16x8 kf0 = *(const bf16x8*)(gb+KOFF + lnid*144 + qid*16);
            bf16x8 kf1 = *(const bf16x8*)(gb+KOFF + lnid*144 + 64 + qid*16);
            // S^T = K . Q^T  (C: row = t = qid*4+reg, col = s = lnid)
            f32x4 st = ZV;
            st = MFMA_BF(kf0, qf0, st);
            st = MFMA_BF(kf1, qf1, st);
            float s0 = st[0]*0.5f, s1 = st[1]*0.5f, s2 = st[2]*0.5f, s3 = st[3]*0.5f;
            float mx = fmaxf(fmaxf(s0,s1), fmaxf(s2,s3));
            float p0 = __expf(s0-mx), p1 = __expf(s1-mx), p2 = __expf(s2-mx), p3 = __expf(s3-mx);
            float inv = 1.f/(p0+p1+p2+p3);
            bool valid = (lnid>>2) == qid;              // block-diagonal mask
            p0 = valid? p0*inv : 0.f;  p1 = valid? p1*inv : 0.f;
            p2 = valid? p2*inv : 0.f;  p3 = valid? p3*inv : 0.f;
            f16x4 pf16 = { (_Float16)p0, (_Float16)p1, (_Float16)p2, (_Float16)p3 };
            // ctx^T[f][s] = V^T . P^T ; P(C-layout) is exactly the f16 B-fragment
            #pragma unroll
            for (int ft=0; ft<4; ++ft){
              f16x4 vf = *(const f16x4*)(gb+VOFF + ((ft*16+lnid)*20 + qid*4)*2);
              f32x4 c = MFMA_H(vf, pf16, ZV);
              unsigned w0 = f2bf(c[0]) | ((unsigned)f2bf(c[1])<<16);
              unsigned w1_ = f2bf(c[2]) | ((unsigned)f2bf(c[3])<<16);
              // write ctx row-major [s][f] into Q buffer (Q is dead now)
              *(uint2*)(gb+QOFF + lnid*144 + (ft*16+qid*4)*2) = make_uint2(w0,w1_);
            }
          }
          asm volatile("" ::: "memory");   // order ctx writes before re-typed reads
          #pragma unroll
          for (int g=0;g<2;++g){
            char* gb = smem + (wid*2+g)*PG;
            bf16x8 c0 = *(const bf16x8*)(gb+QOFF + lnid*144 + qid*16);
            bf16x8 c1 = *(const bf16x8*)(gb+QOFF + lnid*144 + 64 + qid*16);
            #pragma unroll
            for (int nt=0;nt<8;++nt){
              bf16x8 b0 = *(const bf16x8*)(slot + ((nt*16+lnid)*72)*2 + qid*16);
              bf16x8 b1 = *(const bf16x8*)(slot + ((nt*16+lnid)*72 + 32)*2 + qid*16);
              f32x4 a = pacc[g][nt];
              a = MFMA_BF(c0, b0, a);
              a = MFMA_BF(c1, b1, a);
              pacc[g][nt] = a;
            }
          }
        }
      } else if (ph == 16){
        // ---------------- LN1 + FF1 (slot = w1T) ----------------
        #pragma unroll
        for (int g=0;g<2;++g){
          char* gb = smem + (wid*2+g)*PG;
          float mu_[4], rs_[4];
          float sm[4]={0,0,0,0}, sq[4]={0,0,0,0};
          #pragma unroll
          for (int nt=0;nt<8;++nt){
            int col = nt*16+lnid;
            float bov = bo[l*128+col];
            f32x4 a = pacc[g][nt];
            #pragma unroll
            for (int r=0;r<4;++r){
              float xo = bf2f(*(const unsigned short*)(gb+XOFF + (qid*4+r)*272 + col*2));
              float v = a[r] + bov + xo;
              a[r] = v; sm[r]+=v; sq[r]+=v*v;
            }
            pacc[g][nt] = a;
          }
          #pragma unroll
          for (int r=0;r<4;++r){
            float s=sm[r], q=sq[r];
            s += __shfl_xor(s,1); q += __shfl_xor(q,1);
            s += __shfl_xor(s,2); q += __shfl_xor(q,2);
            s += __shfl_xor(s,4); q += __shfl_xor(q,4);
            s += __shfl_xor(s,8); q += __shfl_xor(q,8);
            float mu = s*(1.f/128.f);
            float var = q*(1.f/128.f) - mu*mu;
            mu_[r]=mu; rs_[r]=rsqrtf(var+1e-5f);
          }
          #pragma unroll
          for (int nt=0;nt<8;++nt){
            int col = nt*16+lnid;
            float gv = ln1g[l*128+col], bb = ln1b[l*128+col];
            f32x4 a = pacc[g][nt];
            #pragma unroll
            for (int r=0;r<4;++r){
              float v = (a[r]-mu_[r])*rs_[r]*gv + bb;
              *(unsigned short*)(gb+QOFF + (qid*4+r)*272 + col*2) = f2bf(v); // X2
            }
          }
        }
        asm volatile("" ::: "memory");     // X2 writes before fragment reads
        #pragma unroll
        for (int g=0;g<2;++g){
          char* gb = smem + (wid*2+g)*PG;
          bf16x8 xf[4];
          #pragma unroll
          for (int kc=0;kc<4;++kc)
            xf[kc] = *(const bf16x8*)(gb+QOFF + lnid*272 + kc*64 + qid*16);
          #pragma unroll
          for (int nt=0;nt<4;++nt){
            f32x4 a = ZV;
            #pragma unroll
            for (int kc=0;kc<4;++kc){
              bf16x8 bw = *(const bf16x8*)(slot + ((nt*16+lnid)*136 + kc*32)*2 + qid*16);
              a = MFMA_BF(xf[kc], bw, a);
            }
            float bias = fb1[l*64 + nt*16+lnid];
            #pragma unroll
            for (int r=0;r<4;++r){
              float x = a[r] + bias;
              float gl = 0.5f*x*(1.f + erff(x*0.70710678f));   // exact gelu
              *(unsigned short*)(gb+VOFF + (qid*4+r)*144 + (nt*16+lnid)*2) = f2bf(gl); // h1
            }
          }
        }
      } else {
        // ---------------- FF2 + LN2 (slot = w2T) ----------------
        #pragma unroll
        for (int g=0;g<2;++g){
          char* gb = smem + (wid*2+g)*PG;
          bf16x8 hf0 = *(const bf16x8*)(gb+VOFF + lnid*144 + qid*16);
          bf16x8 hf1 = *(const bf16x8*)(gb+VOFF + lnid*144 + 64 + qid*16);
          f32x4 racc[8];
          #pragma unroll
          for (int nt=0;nt<8;++nt){
            f32x4 a = ZV;
            bf16x8 b0 = *(const bf16x8*)(slot + ((nt*16+lnid)*72)*2 + qid*16);
            bf16x8 b1 = *(const bf16x8*)(slot + ((nt*16+lnid)*72+32)*2 + qid*16);
            a = MFMA_BF(hf0, b0, a);
            a = MFMA_BF(hf1, b1, a);
            racc[nt] = a;
          }
          float mu_[4], rs_[4];
          float sm[4]={0,0,0,0}, sq[4]={0,0,0,0};
          #pragma unroll
          for (int nt=0;nt<8;++nt){
            int col = nt*16+lnid;
            float b2v = fb2[l*128+col];
            #pragma unroll
            for (int r=0;r<4;++r){
              float xo = bf2f(*(const unsigned short*)(gb+XOFF + (qid*4+r)*272 + col*2));
              float v = racc[nt][r] + b2v + xo;
              racc[nt][r] = v; sm[r]+=v; sq[r]+=v*v;
            }
          }
          #pragma unroll
          for (int r=0;r<4;++r){
            float s=sm[r], q=sq[r];
            s += __shfl_xor(s,1); q += __shfl_xor(q,1);
            s += __shfl_xor(s,2); q += __shfl_xor(q,2);
            s += __shfl_xor(s,4); q += __shfl_xor(q,4);
            s += __shfl_xor(s,8); q += __shfl_xor(q,8);
            float mu = s*(1.f/128.f);
            float var = q*(1.f/128.f) - mu*mu;
            mu_[r]=mu; rs_[r]=rsqrtf(var+1e-5f);
          }
          #pragma unroll
          for (int nt=0;nt<8;++nt){
            int col = nt*16+lnid;
            float gv = ln2g[l*128+col], bb = ln2b[l*128+col];
            #pragma unroll
            for (int r=0;r<4;++r){
              float v = (racc[nt][r]-mu_[r])*rs_[r]*gv + bb;
              *(unsigned short*)(gb+XOFF + (qid*4+r)*272 + col*2) = f2bf(v); // new x
            }
          }
        }
      }

      // commit prefetched stage into the other slot, then barrier
      if (nn16 > 0){
        char* ns = smem + WSOFF + ((sidx+1)&1)*SLOTSZ;
        #pragma unroll
        for (int i=0;i<5;++i){ int idx=i*256+tid; if (idx<nn16) *(uint4*)(ns+idx*16) = pfbuf[i]; }
      }
      __syncthreads();
      ++sidx;
    }
  }

  // ---- epilogue: final_embedding = mean over the 4 seq rows ----
  {
    int bl = lane>>3;                 // batch within wave 0..7
    int d0 = (lane&7)*16;
    int g  = wid*2 + (bl>>2);
    char* Xb = smem + g*PG + XOFF;
    int r0 = (bl&3)*4;
    float acc[16];
    #pragma unroll
    for (int j=0;j<16;++j) acc[j]=0.f;
    #pragma unroll
    for (int s=0;s<4;++s){
      #pragma unroll
      for (int j=0;j<16;++j)
        acc[j] += bf2f(*(const unsigned short*)(Xb + (r0+s)*272 + (d0+j)*2));
    }
    float* dst = out + (size_t)(batch0 + wid*8 + bl)*128 + d0;
    #pragma unroll
    for (int j=0;j<4;++j){
      float4 v = { acc[j*4]*0.25f, acc[j*4+1]*0.25f, acc[j*4+2]*0.25f, acc[j*4+3]*0.25f };
      *(float4*)(dst + j*4) = v;
    }
  }
}

extern "C" void kernel_launch(void* const* d_in, const int* in_sizes, int n_in,
                              void* d_out, int out_size, void* d_ws, size_t ws_size,
                              hipStream_t stream) {
  const float* emb  = (const float*)d_in[0];
  const float* wq   = (const float*)d_in[1];
  const float* bq   = (const float*)d_in[2];
  const float* wk   = (const float*)d_in[3];
  const float* bk   = (const float*)d_in[4];
  const float* wv   = (const float*)d_in[5];
  const float* bv   = (const float*)d_in[6];
  const float* wo   = (const float*)d_in[7];
  const float* bo   = (const float*)d_in[8];
  const float* ln1g = (const float*)d_in[9];
  const float* ln1b = (const float*)d_in[10];
  const float* fw1  = (const float*)d_in[11];
  const float* fb1  = (const float*)d_in[12];
  const float* fw2  = (const float*)d_in[13];
  const float* fb2  = (const float*)d_in[14];
  const float* ln2g = (const float*)d_in[15];
  const float* ln2b = (const float*)d_in[16];
  unsigned short* ws = (unsigned short*)d_ws;
  float* out = (float*)d_out;

  prep_kernel<<<(WTOT+255)/256, 256, 0, stream>>>(wq, wk, wv, wo, fw1, fw2, ws);
  bert_kernel<<<1024, 256, 0, stream>>>(emb, bq, bk, bv, bo, ln1g, ln1b,
                                        fb1, fb2, ln2g, ln2b, ws, out);
}

// Round 4
// 636.965 us; speedup vs baseline: 2.0962x; 2.0962x over previous
//
#include <hip/hip_runtime.h>
#include <stdint.h>

// ---------------------------------------------------------------------------
// Fused 4-layer mini-BERT (B=32768, SEQ=4, D=128, H=4, DH=64) for gfx950.
// Round 4 (= round-2 design, compile-fixed x2): 16 batches/WG, 2048 WGs,
// 77 KB LDS -> 2 WGs/CU. Weight tiles pre-packed to MFMA fragment order
// (16 KB each, read as slot + chunk*1024 + lane*16, conflict-free b128).
// All GEMMs except V produce C^T (lane = row s = lnid, regs = 4 contiguous
// cols) so every activation store/load is a vector ds op and LN stats take
// 2 shuffles.
// ---------------------------------------------------------------------------

typedef __attribute__((ext_vector_type(8))) short    bf16x8;  // 8 bf16
typedef __attribute__((ext_vector_type(4))) _Float16 f16x4;
typedef __attribute__((ext_vector_type(4))) float    f32x4;

#define MFMA_BF(a,b,c) __builtin_amdgcn_mfma_f32_16x16x32_bf16((a),(b),(c),0,0,0)
#define MFMA_H(a,b,c)  __builtin_amdgcn_mfma_f32_16x16x16f16((a),(b),(c),0,0,0)

__device__ __forceinline__ unsigned short f2bf(float f){
  unsigned u = __float_as_uint(f);
  u += 0x7FFFu + ((u>>16)&1u);          // RNE
  return (unsigned short)(u>>16);
}
__device__ __forceinline__ unsigned pk2bf(float a, float b){
  return (unsigned)f2bf(a) | ((unsigned)f2bf(b)<<16);
}
__device__ __forceinline__ unsigned pkh(float a, float b){
  auto h = __builtin_amdgcn_cvt_pkrtz(a, b);    // v_cvt_pkrtz_f16_f32
  return __builtin_bit_cast(unsigned, h);
}
__device__ __forceinline__ void ubf2(unsigned u, float& a, float& b){
  a = __uint_as_float(u<<16);
  b = __uint_as_float(u & 0xffff0000u);
}

// ---------------- ws layout: 72 tiles of 8192 bf16 (16 KB), stage order -----
// tile t = l*18 + r;  r = h*4 + {0:wq,1:wk,2:wv,3:wo}, r=16:w1, r=17:w2.
// Each tile: 16 chunks of 512 elems; chunk c, lane, j ->
//   qkv/w1 (A/B-frag, m/n = f): f=(c>>2)*16+lnid, k=d=(c&3)*32+qid*8+j
//   wo/w2  (A-frag,   m = d) : d=(c>>1)*16+lnid, k=(c&1)*32+qid*8+j
__global__ __launch_bounds__(256) void prep_kernel(
    const float* __restrict__ wq, const float* __restrict__ wk,
    const float* __restrict__ wv, const float* __restrict__ wo,
    const float* __restrict__ w1, const float* __restrict__ w2,
    unsigned short* __restrict__ ws){
  int e16 = blockIdx.x*256 + threadIdx.x;       // 0..73727 (one uint4 each)
  int t    = e16 >> 10;
  int c    = (e16 >> 6) & 15;
  int lane = e16 & 63;
  int lnid = lane & 15, qid = lane >> 4;
  int l = t/18, r = t - l*18;
  float v[8];
  if (r < 16){
    int h = r >> 2, ty = r & 3;
    if (ty < 3){
      const float* W = (ty==0? wq : (ty==1? wk : wv)) + (size_t)(l*4+h)*8192;
      int f = (c>>2)*16 + lnid, d0 = (c&3)*32 + qid*8;
      #pragma unroll
      for (int j=0;j<8;++j) v[j] = W[(d0+j)*64 + f];
    } else {
      const float* W = wo + (size_t)l*32768 + (size_t)h*8192;  // rows h*64..
      int dd = (c>>1)*16 + lnid, k0 = (c&1)*32 + qid*8;
      #pragma unroll
      for (int j=0;j<8;++j) v[j] = W[(k0+j)*128 + dd];
    }
  } else if (r == 16){
    const float* W = w1 + (size_t)l*8192;
    int f = (c>>2)*16 + lnid, d0 = (c&3)*32 + qid*8;
    #pragma unroll
    for (int j=0;j<8;++j) v[j] = W[(d0+j)*64 + f];
  } else {
    const float* W = w2 + (size_t)l*8192;
    int dd = (c>>1)*16 + lnid, k0 = (c&1)*32 + qid*8;
    #pragma unroll
    for (int j=0;j<8;++j) v[j] = W[(k0+j)*128 + dd];
  }
  uint4 o;
  o.x = pk2bf(v[0],v[1]); o.y = pk2bf(v[2],v[3]);
  o.z = pk2bf(v[4],v[5]); o.w = pk2bf(v[6],v[7]);
  ((uint4*)ws)[e16] = o;
}

// ---------------- LDS layout (per group of 16 rows, stride PG) --------------
//  XOFF: X residual  bf16 [16][pitch 136]           4352 B
//  QOFF: Q [16][72] / ctx [16][72] / X2 [16][136] (spills into K region)
//  KOFF: K [16][72]
//  VOFF: V^T f16 [64][20] (2560 B) / h1 bf16 [16][72]
#define XOFF  0
#define QOFF  4352
#define KOFF  6656
#define VOFF  8960
#define PG    11520
#define WSOFF 46080
#define SLOTSZ 16384
#define LDSSZ 78848

__global__ __launch_bounds__(256,2) void bert_kernel(
    const float* __restrict__ emb,
    const float* __restrict__ bq, const float* __restrict__ bk, const float* __restrict__ bv,
    const float* __restrict__ bo,
    const float* __restrict__ ln1g, const float* __restrict__ ln1b,
    const float* __restrict__ fb1, const float* __restrict__ fb2,
    const float* __restrict__ ln2g, const float* __restrict__ ln2b,
    const unsigned short* __restrict__ ws,
    float* __restrict__ out)
{
  __shared__ __align__(16) char smem[LDSSZ];
  const int tid  = threadIdx.x;
  const int wid  = tid>>6;
  const int lane = tid&63;
  const int lnid = lane&15;
  const int qid  = lane>>4;
  const int batch0 = blockIdx.x*16;
  char* gb = smem + wid*PG;
  const f32x4 ZV = {0.f,0.f,0.f,0.f};

  // ---- initial X: embeddings[:, :4, :] -> bf16 LDS row-major [16][136] ----
  {
    int row = lane>>2, colq = (lane&3)*32;
    const float* src = emb + ((size_t)(batch0 + wid*4 + (row>>2))*6 + (row&3))*128 + colq;
    #pragma unroll
    for (int i=0;i<8;++i){
      float4 v = *(const float4*)(src + i*4);
      uint2 u; u.x = pk2bf(v.x,v.y); u.y = pk2bf(v.z,v.w);
      *(uint2*)(gb + XOFF + row*272 + (colq+i*4)*2) = u;
    }
  }
  // ---- passthrough: rows 4 (positive) and 5 (negatives) ----
  {
    const float* eb = emb + (size_t)batch0*768;
    float* o1 = out + 4194304 + (size_t)batch0*128;
    float* o2 = out + 8388608 + (size_t)batch0*128;
    #pragma unroll
    for (int i=0;i<4;++i){
      int idx = i*256 + tid;           // 0..1023 float4s
      int b = idx>>6, rem = idx&63;
      float4 v = *(const float4*)(eb + b*768 + 512 + rem*4);
      if (rem<32) *(float4*)(o1 + b*128 + rem*4) = v;
      else        *(float4*)(o2 + b*128 + (rem-32)*4) = v;
    }
  }

  // ---- prologue: stage tile 0 into slot 0 ----
  const uint4* wsv = (const uint4*)ws;
  {
    #pragma unroll
    for (int i=0;i<4;++i)
      *(uint4*)(smem + WSOFF + (i*256+tid)*16) = wsv[i*256+tid];
  }
  __syncthreads();

  f32x4  pacc[8];
  bf16x8 xfrag[4];
  int sidx = 0;

  for (int l=0; l<4; ++l){
    #pragma unroll
    for (int kc=0;kc<4;++kc)
      xfrag[kc] = *(const bf16x8*)(gb + XOFF + lnid*272 + kc*64 + qid*16);
    #pragma unroll
    for (int nt=0;nt<8;++nt) pacc[nt] = ZV;

    for (int ph=0; ph<18; ++ph){
      char* slot = smem + WSOFF + (sidx&1)*SLOTSZ;

      // prefetch next weight tile into registers
      uint4 pf0,pf1,pf2,pf3;
      bool havepf = (sidx+1 < 72);
      if (havepf){
        const uint4* p = wsv + (size_t)(sidx+1)*1024 + tid;
        pf0 = p[0]; pf1 = p[256]; pf2 = p[512]; pf3 = p[768];
      }

      if (ph < 16){
        int h = ph>>2, t = ph&3;
        if (t < 2){
          // ---- Q^T / K^T = W^T · X^T : A = W-frag, B = X-frag ----
          char* dst = gb + (t? KOFF : QOFF);
          const float* bias_base = (t? bk : bq) + (l*4+h)*64;
          #pragma unroll
          for (int nt=0; nt<4; ++nt){
            f32x4 a = ZV;
            #pragma unroll
            for (int kc=0; kc<4; ++kc){
              bf16x8 wf = *(const bf16x8*)(slot + (nt*4+kc)*1024 + lane*16);
              a = MFMA_BF(wf, xfrag[kc], a);
            }
            f32x4 bs = *(const f32x4*)(bias_base + nt*16 + qid*4);
            uint2 u; u.x = pk2bf(a[0]+bs[0], a[1]+bs[1]);
                     u.y = pk2bf(a[2]+bs[2], a[3]+bs[3]);
            *(uint2*)(dst + lnid*144 + nt*32 + qid*8) = u;   // [s][f] row-major
          }
        } else if (t == 2){
          // ---- V = X · Wv (unflipped): C regs = 4 rows s at col f -> V^T ----
          const float* bias_base = bv + (l*4+h)*64;
          #pragma unroll
          for (int nt=0; nt<4; ++nt){
            f32x4 a = ZV;
            #pragma unroll
            for (int kc=0; kc<4; ++kc){
              bf16x8 wf = *(const bf16x8*)(slot + (nt*4+kc)*1024 + lane*16);
              a = MFMA_BF(xfrag[kc], wf, a);
            }
            float b = bias_base[nt*16 + lnid];
            uint2 u; u.x = pkh(a[0]+b, a[1]+b);
                     u.y = pkh(a[2]+b, a[3]+b);
            *(uint2*)(gb + VOFF + (nt*16+lnid)*40 + qid*8) = u;  // V^T[f][s]
          }
        } else {
          // ---- attention + proj partial (slot = wo tile for head h) ----
          bf16x8 kf0 = *(const bf16x8*)(gb+KOFF + lnid*144 + qid*16);
          bf16x8 kf1 = *(const bf16x8*)(gb+KOFF + lnid*144 + 64 + qid*16);
          bf16x8 qf0 = *(const bf16x8*)(gb+QOFF + lnid*144 + qid*16);
          bf16x8 qf1 = *(const bf16x8*)(gb+QOFF + lnid*144 + 64 + qid*16);
          // S^T[t][s] = K·Q^T : lane (col s=lnid) holds t = qid*4+r
          f32x4 st = MFMA_BF(kf0, qf0, ZV);
          st = MFMA_BF(kf1, qf1, st);
          float s0=st[0]*0.5f, s1=st[1]*0.5f, s2=st[2]*0.5f, s3=st[3]*0.5f;
          float mx = fmaxf(fmaxf(s0,s1), fmaxf(s2,s3));
          float p0=__expf(s0-mx), p1=__expf(s1-mx), p2=__expf(s2-mx), p3=__expf(s3-mx);
          float inv = 1.f/(p0+p1+p2+p3);
          bool valid = (lnid>>2) == qid;          // block-diagonal (4-batch tile)
          p0 = valid? p0*inv:0.f; p1 = valid? p1*inv:0.f;
          p2 = valid? p2*inv:0.f; p3 = valid? p3*inv:0.f;
          union { unsigned u[2]; f16x4 h4; } pu;
          pu.u[0] = pkh(p0,p1);
          pu.u[1] = pkh(p2,p3);
          f16x4 pf = pu.h4;                        // B-frag of 16x16x16 f16
          #pragma unroll
          for (int ft=0; ft<4; ++ft){
            f16x4 vf = *(const f16x4*)(gb+VOFF + (ft*16+lnid)*40 + qid*8);
            f32x4 c = MFMA_H(vf, pf, ZV);          // ctx^T[f][s]
            uint2 u; u.x = pk2bf(c[0],c[1]); u.y = pk2bf(c[2],c[3]);
            *(uint2*)(gb+QOFF + lnid*144 + ft*32 + qid*8) = u;  // ctx[s][f] over Q
          }
          asm volatile("" ::: "memory");
          bf16x8 c0 = *(const bf16x8*)(gb+QOFF + lnid*144 + qid*16);
          bf16x8 c1 = *(const bf16x8*)(gb+QOFF + lnid*144 + 64 + qid*16);
          #pragma unroll
          for (int nt=0; nt<8; ++nt){
            bf16x8 w0 = *(const bf16x8*)(slot + (nt*2+0)*1024 + lane*16);
            bf16x8 w1f= *(const bf16x8*)(slot + (nt*2+1)*1024 + lane*16);
            f32x4 a = pacc[nt];
            a = MFMA_BF(w0, c0, a);
            a = MFMA_BF(w1f, c1, a);
            pacc[nt] = a;                           // proj^T: (s=lnid, d regs)
          }
        }
      } else if (ph == 16){
        // ---- +bo +residual, LN1, FF1+GELU (slot = w1 tile) ----
        float sm=0.f, sq=0.f;
        #pragma unroll
        for (int nt=0;nt<8;++nt){
          f32x4 b4 = *(const f32x4*)(bo + l*128 + nt*16 + qid*4);
          uint2 xr = *(const uint2*)(gb+XOFF + lnid*272 + nt*32 + qid*8);
          float x0,x1,x2,x3; ubf2(xr.x,x0,x1); ubf2(xr.y,x2,x3);
          f32x4 a = pacc[nt];
          a[0]+=b4[0]+x0; a[1]+=b4[1]+x1; a[2]+=b4[2]+x2; a[3]+=b4[3]+x3;
          sm += a[0]+a[1]+a[2]+a[3];
          sq += a[0]*a[0]+a[1]*a[1]+a[2]*a[2]+a[3]*a[3];
          pacc[nt] = a;
        }
        sm += __shfl_xor(sm,16); sq += __shfl_xor(sq,16);
        sm += __shfl_xor(sm,32); sq += __shfl_xor(sq,32);
        float mu = sm*(1.f/128.f);
        float rs = rsqrtf(sq*(1.f/128.f) - mu*mu + 1e-5f);
        #pragma unroll
        for (int nt=0;nt<8;++nt){
          f32x4 g4 = *(const f32x4*)(ln1g + l*128 + nt*16 + qid*4);
          f32x4 be = *(const f32x4*)(ln1b + l*128 + nt*16 + qid*4);
          f32x4 a = pacc[nt];
          float v0 = (a[0]-mu)*rs*g4[0]+be[0];
          float v1 = (a[1]-mu)*rs*g4[1]+be[1];
          float v2 = (a[2]-mu)*rs*g4[2]+be[2];
          float v3 = (a[3]-mu)*rs*g4[3]+be[3];
          uint2 u; u.x = pk2bf(v0,v1); u.y = pk2bf(v2,v3);
          *(uint2*)(gb+QOFF + lnid*272 + nt*32 + qid*8) = u;   // X2 [16][136]
        }
        asm volatile("" ::: "memory");
        bf16x8 x2f[4];
        #pragma unroll
        for (int kc=0;kc<4;++kc)
          x2f[kc] = *(const bf16x8*)(gb+QOFF + lnid*272 + kc*64 + qid*16);
        #pragma unroll
        for (int nt=0; nt<4; ++nt){
          f32x4 a = ZV;
          #pragma unroll
          for (int kc=0; kc<4; ++kc){
            bf16x8 wf = *(const bf16x8*)(slot + (nt*4+kc)*1024 + lane*16);
            a = MFMA_BF(wf, x2f[kc], a);
          }
          f32x4 b1 = *(const f32x4*)(fb1 + l*64 + nt*16 + qid*4);
          float g0,g1,g2,g3;
          { float x = a[0]+b1[0]; g0 = 0.5f*x*(1.f+erff(x*0.70710678f)); }
          { float x = a[1]+b1[1]; g1 = 0.5f*x*(1.f+erff(x*0.70710678f)); }
          { float x = a[2]+b1[2]; g2 = 0.5f*x*(1.f+erff(x*0.70710678f)); }
          { float x = a[3]+b1[3]; g3 = 0.5f*x*(1.f+erff(x*0.70710678f)); }
          uint2 u; u.x = pk2bf(g0,g1); u.y = pk2bf(g2,g3);
          *(uint2*)(gb+VOFF + lnid*144 + nt*32 + qid*8) = u;   // h1 [16][72]
        }
      } else {
        // ---- FF2 + residual + LN2 -> new X (slot = w2 tile) ----
        bf16x8 h0  = *(const bf16x8*)(gb+VOFF + lnid*144 + qid*16);
        bf16x8 h1f = *(const bf16x8*)(gb+VOFF + lnid*144 + 64 + qid*16);
        f32x4 racc[8];
        #pragma unroll
        for (int nt=0; nt<8; ++nt){
          bf16x8 w0 = *(const bf16x8*)(slot + (nt*2+0)*1024 + lane*16);
          bf16x8 w1f= *(const bf16x8*)(slot + (nt*2+1)*1024 + lane*16);
          f32x4 a = MFMA_BF(w0, h0, ZV);
          a = MFMA_BF(w1f, h1f, a);
          racc[nt] = a;
        }
        float sm=0.f, sq=0.f;
        #pragma unroll
        for (int nt=0;nt<8;++nt){
          f32x4 b4 = *(const f32x4*)(fb2 + l*128 + nt*16 + qid*4);
          uint2 xr = *(const uint2*)(gb+XOFF + lnid*272 + nt*32 + qid*8);
          float x0,x1,x2,x3; ubf2(xr.x,x0,x1); ubf2(xr.y,x2,x3);
          f32x4 a = racc[nt];
          a[0]+=b4[0]+x0; a[1]+=b4[1]+x1; a[2]+=b4[2]+x2; a[3]+=b4[3]+x3;
          sm += a[0]+a[1]+a[2]+a[3];
          sq += a[0]*a[0]+a[1]*a[1]+a[2]*a[2]+a[3]*a[3];
          racc[nt] = a;
        }
        sm += __shfl_xor(sm,16); sq += __shfl_xor(sq,16);
        sm += __shfl_xor(sm,32); sq += __shfl_xor(sq,32);
        float mu = sm*(1.f/128.f);
        float rs = rsqrtf(sq*(1.f/128.f) - mu*mu + 1e-5f);
        #pragma unroll
        for (int nt=0;nt<8;++nt){
          f32x4 g4 = *(const f32x4*)(ln2g + l*128 + nt*16 + qid*4);
          f32x4 be = *(const f32x4*)(ln2b + l*128 + nt*16 + qid*4);
          f32x4 a = racc[nt];
          float v0 = (a[0]-mu)*rs*g4[0]+be[0];
          float v1 = (a[1]-mu)*rs*g4[1]+be[1];
          float v2 = (a[2]-mu)*rs*g4[2]+be[2];
          float v3 = (a[3]-mu)*rs*g4[3]+be[3];
          uint2 u; u.x = pk2bf(v0,v1); u.y = pk2bf(v2,v3);
          *(uint2*)(gb+XOFF + lnid*272 + nt*32 + qid*8) = u;   // new X
        }
      }

      // commit prefetched tile into the other slot, then barrier
      if (havepf){
        char* ns = smem + WSOFF + ((sidx+1)&1)*SLOTSZ;
        uint4* q = (uint4*)(ns) + tid;
        q[0]=pf0; q[256]=pf1; q[512]=pf2; q[768]=pf3;
      }
      __syncthreads();
      ++sidx;
    }
  }

  // ---- epilogue: final_embedding = mean over 4 seq rows ----
  {
    int bl = lane>>4;                 // batch within group
    float acc[8] = {0,0,0,0,0,0,0,0};
    #pragma unroll
    for (int s=0;s<4;++s){
      uint4 u = *(const uint4*)(gb + XOFF + (bl*4+s)*272 + lnid*16);
      float a0,a1;
      ubf2(u.x,a0,a1); acc[0]+=a0; acc[1]+=a1;
      ubf2(u.y,a0,a1); acc[2]+=a0; acc[3]+=a1;
      ubf2(u.z,a0,a1); acc[4]+=a0; acc[5]+=a1;
      ubf2(u.w,a0,a1); acc[6]+=a0; acc[7]+=a1;
    }
    float* dst = out + (size_t)(batch0 + wid*4 + bl)*128 + lnid*8;
    f32x4 v0 = {acc[0]*0.25f, acc[1]*0.25f, acc[2]*0.25f, acc[3]*0.25f};
    f32x4 v1 = {acc[4]*0.25f, acc[5]*0.25f, acc[6]*0.25f, acc[7]*0.25f};
    *(f32x4*)dst = v0;
    *(f32x4*)(dst+4) = v1;
  }
}

extern "C" void kernel_launch(void* const* d_in, const int* in_sizes, int n_in,
                              void* d_out, int out_size, void* d_ws, size_t ws_size,
                              hipStream_t stream) {
  const float* emb  = (const float*)d_in[0];
  const float* wq   = (const float*)d_in[1];
  const float* bq   = (const float*)d_in[2];
  const float* wk   = (const float*)d_in[3];
  const float* bk   = (const float*)d_in[4];
  const float* wv   = (const float*)d_in[5];
  const float* bv   = (const float*)d_in[6];
  const float* wo   = (const float*)d_in[7];
  const float* bo   = (const float*)d_in[8];
  const float* ln1g = (const float*)d_in[9];
  const float* ln1b = (const float*)d_in[10];
  const float* fw1  = (const float*)d_in[11];
  const float* fb1  = (const float*)d_in[12];
  const float* fw2  = (const float*)d_in[13];
  const float* fb2  = (const float*)d_in[14];
  const float* ln2g = (const float*)d_in[15];
  const float* ln2b = (const float*)d_in[16];
  unsigned short* ws = (unsigned short*)d_ws;
  float* out = (float*)d_out;

  prep_kernel<<<288, 256, 0, stream>>>(wq, wk, wv, wo, fw1, fw2, ws);
  bert_kernel<<<2048, 256, 0, stream>>>(emb, bq, bk, bv, bo, ln1g, ln1b,
                                        fb1, fb2, ln2g, ln2b, ws, out);
}